// Round 1
// baseline (1258.963 us; speedup 1.0000x reference)
//
#include <hip/hip_runtime.h>

#define HW 256
#define NF 32
#define TCOLS 8

// ---- monotone float<->uint encoding so atomicMax(uint) == float max ----
__device__ __forceinline__ unsigned enc(float f) {
  unsigned u = __float_as_uint(f);
  return u ^ (0x80000000u | (unsigned)((int)u >> 31));
}
__device__ __forceinline__ float dec(unsigned k) {
  unsigned b = (k & 0x80000000u) ? (k ^ 0x80000000u) : ~k;
  return __uint_as_float(b);
}

// one recurrence element: normalize gates, then
// h = (1-a-b-c)*x + a*h[k-1] + b*h[k] + c*h[k+1]
__device__ __forceinline__ float stepf(float a, float b, float c, float xm,
                                       float hm, float hc, float hp) {
  float s = fabsf(a) + fabsf(b) + fabsf(c) + 1e-7f;
  float inv = __builtin_amdgcn_rcpf(s);
  if (s < 1.0f) inv = 1.0f;
  a *= inv; b *= inv; c *= inv;
  float h = (1.0f - a - b - c) * xm;
  h = fmaf(a, hm, h);
  h = fmaf(b, hc, h);
  h = fmaf(c, hp, h);
  return h;
}

__global__ __launch_bounds__(256) void spn_scan(
    const float* __restrict__ x, const float* __restrict__ mask,
    unsigned* __restrict__ out) {
  const int bid = blockIdx.x;
  const int tid = threadIdx.x;
  __shared__ float tl[4][TCOLS][HW];  // [plane][col][row], transposed tiles
  __shared__ float hb[2][HW + 2];     // h exchange, padded zeros at both ends

  const size_t plane = (size_t)HW * HW;

  if (bid < 256) {
    // ---------- horizontal dirs 0 (fwd) / 1 (rev): scan w, cross dim h=tid --
    const int dir = bid >> 7;
    const int rem = bid & 127;
    const int b = rem >> 5, ch = rem & 31;
    const bool rev = (dir == 1);
    const float* g1p = x + ((size_t)b * 12 * NF + (3 * dir + 0) * NF + ch) * plane;
    const float* g2p = x + ((size_t)b * 12 * NF + (3 * dir + 1) * NF + ch) * plane;
    const float* g3p = x + ((size_t)b * 12 * NF + (3 * dir + 2) * NF + ch) * plane;
    const float* mp  = mask + ((size_t)b * NF + ch) * plane;
    unsigned* op = out + ((size_t)b * NF + ch) * plane;

    for (int i = tid; i < 2 * (HW + 2); i += 256) (&hb[0][0])[i] = 0.0f;

    float hreg = 0.0f;
    int cur = 0;
    const int r0 = tid >> 1, cc = tid & 1;  // 2 threads per row for tile loads
    const float* ps[4] = {g1p, g2p, g3p, mp};
    for (int tile = 0; tile < HW / TCOLS; ++tile) {
      const int t0 = rev ? (HW - TCOLS - tile * TCOLS) : (tile * TCOLS);
      __syncthreads();  // prior readers done (also publishes hb init)
#pragma unroll
      for (int p = 0; p < 4; ++p) {
#pragma unroll
        for (int half = 0; half < 2; ++half) {
          const int r = r0 + half * 128;
          const float4 v = *(const float4*)(ps[p] + (size_t)r * HW + t0 + cc * 4);
          tl[p][cc * 4 + 0][r] = v.x;
          tl[p][cc * 4 + 1][r] = v.y;
          tl[p][cc * 4 + 2][r] = v.z;
          tl[p][cc * 4 + 3][r] = v.w;
        }
      }
      __syncthreads();
      for (int j = 0; j < TCOLS; ++j) {
        const int col = rev ? (TCOLS - 1 - j) : j;
        const int t = t0 + col;
        const float a  = tl[0][col][tid];
        const float g2 = tl[1][col][tid];
        const float c  = tl[2][col][tid];
        const float xm = tl[3][col][tid];
        const float hm = hb[cur][tid];
        const float hp = hb[cur][tid + 2];
        const float h = stepf(a, g2, c, xm, hm, hreg, hp);
        hb[cur ^ 1][tid + 1] = h;
        hreg = h;
        atomicMax(op + (size_t)tid * HW + t, enc(h));
        __syncthreads();  // publish hb[cur^1]; protect WAR on hb[cur]
        cur ^= 1;
      }
    }
  } else {
    // ---------- vertical dirs 2 (fwd) / 3 (rev): one wave per slice ---------
    if (tid >= 64) return;  // no __syncthreads in this path
    const int lane = tid;
    const int vb = bid - 256;
    const int dir = 2 + (vb >> 7);
    const int rem = vb & 127;
    const int b = rem >> 5, ch = rem & 31;
    const bool rev = (dir == 3);
    const float* g1p = x + ((size_t)b * 12 * NF + (3 * dir + 0) * NF + ch) * plane;
    const float* g2p = x + ((size_t)b * 12 * NF + (3 * dir + 1) * NF + ch) * plane;
    const float* g3p = x + ((size_t)b * 12 * NF + (3 * dir + 2) * NF + ch) * plane;
    const float* mp  = mask + ((size_t)b * NF + ch) * plane;
    unsigned* op = out + ((size_t)b * NF + ch) * plane;

    float4 hv = {0.f, 0.f, 0.f, 0.f};
    int t = rev ? (HW - 1) : 0;
    const int koff = lane * 4;  // lane owns w = 4*lane .. 4*lane+3
    float4 a4 = *(const float4*)(g1p + (size_t)t * HW + koff);
    float4 b4 = *(const float4*)(g2p + (size_t)t * HW + koff);
    float4 c4 = *(const float4*)(g3p + (size_t)t * HW + koff);
    float4 x4 = *(const float4*)(mp  + (size_t)t * HW + koff);
    for (int step = 0; step < HW; ++step) {
      const float4 A = a4, B = b4, C = c4, X = x4;
      const int tn = rev ? (HW - 2 - step) : (step + 1);
      if (step + 1 < HW) {  // software prefetch next row
        a4 = *(const float4*)(g1p + (size_t)tn * HW + koff);
        b4 = *(const float4*)(g2p + (size_t)tn * HW + koff);
        c4 = *(const float4*)(g3p + (size_t)tn * HW + koff);
        x4 = *(const float4*)(mp  + (size_t)tn * HW + koff);
      }
      float left = __shfl_up(hv.w, 1);
      if (lane == 0) left = 0.f;
      float right = __shfl_down(hv.x, 1);
      if (lane == 63) right = 0.f;
      float4 hn;
      hn.x = stepf(A.x, B.x, C.x, X.x, left, hv.x, hv.y);
      hn.y = stepf(A.y, B.y, C.y, X.y, hv.x, hv.y, hv.z);
      hn.z = stepf(A.z, B.z, C.z, X.z, hv.y, hv.z, hv.w);
      hn.w = stepf(A.w, B.w, C.w, X.w, hv.z, hv.w, right);
      unsigned* o = op + (size_t)t * HW + koff;
      atomicMax(o + 0, enc(hn.x));
      atomicMax(o + 1, enc(hn.y));
      atomicMax(o + 2, enc(hn.z));
      atomicMax(o + 3, enc(hn.w));
      hv = hn;
      t = tn;
    }
  }
}

__global__ __launch_bounds__(256) void spn_decode(unsigned* __restrict__ o) {
  const int i = blockIdx.x * 256 + threadIdx.x;
  uint4 v = ((uint4*)o)[i];
  float4 f;
  f.x = dec(v.x); f.y = dec(v.y); f.z = dec(v.z); f.w = dec(v.w);
  ((float4*)o)[i] = f;
}

extern "C" void kernel_launch(void* const* d_in, const int* in_sizes, int n_in,
                              void* d_out, int out_size, void* d_ws, size_t ws_size,
                              hipStream_t stream) {
  const float* x = (const float*)d_in[0];     // [4,384,256,256] f32
  const float* mask = (const float*)d_in[1];  // [4,32,256,256] f32
  (void)d_ws; (void)ws_size; (void)in_sizes; (void)n_in;
  // init d_out to encoded -NaN (0x0 is the minimum of the monotone encoding)
  hipMemsetAsync(d_out, 0, (size_t)out_size * sizeof(float), stream);
  spn_scan<<<512, 256, 0, stream>>>(x, mask, (unsigned*)d_out);
  spn_decode<<<out_size / 1024, 256, 0, stream>>>((unsigned*)d_out);
}

// Round 2
// 777.291 us; speedup vs baseline: 1.6197x; 1.6197x over previous
//
#include <hip/hip_runtime.h>

#define HW 256
#define NF 32
#define TCOLS 8

// ---- monotone float<->uint encoding so atomicMax(uint) == float max ----
__device__ __forceinline__ unsigned enc(float f) {
  unsigned u = __float_as_uint(f);
  return u ^ (0x80000000u | (unsigned)((int)u >> 31));
}
__device__ __forceinline__ float dec(unsigned k) {
  unsigned b = (k & 0x80000000u) ? (k ^ 0x80000000u) : ~k;
  return __uint_as_float(b);
}

// one recurrence element: normalize gates, then
// h = (1-a-b-c)*x + a*h[k-1] + b*h[k] + c*h[k+1]
__device__ __forceinline__ float stepf(float a, float b, float c, float xm,
                                       float hm, float hc, float hp) {
  float s = fabsf(a) + fabsf(b) + fabsf(c) + 1e-7f;
  float inv = __builtin_amdgcn_rcpf(s);
  if (s < 1.0f) inv = 1.0f;
  a *= inv; b *= inv; c *= inv;
  float h = (1.0f - a - b - c) * xm;
  h = fmaf(a, hm, h);
  h = fmaf(b, hc, h);
  h = fmaf(c, hp, h);
  return h;
}

// ======================= fast path: per-direction ws buffers ================
// grid: blocks 0..255 = horizontal (dir 0/1), blocks 256..319 = vertical
// (dir 2/3, 4 slices per block, one wave each).
__global__ __launch_bounds__(256) void spn_scan_ws(
    const float* __restrict__ x, const float* __restrict__ mask,
    float* __restrict__ ws) {
  const int bid = blockIdx.x;
  const int tid = threadIdx.x;
  const size_t plane = (size_t)HW * HW;
  const size_t P = (size_t)4 * NF * plane;  // one direction buffer

  if (bid < 256) {
    // ---------- horizontal dirs 0 (fwd) / 1 (rev): scan w, cross dim h=tid --
    __shared__ float tl[4][TCOLS][HW];  // [plane][col][row], transposed tiles
    __shared__ float hb[2][HW + 2];     // h exchange, padded zeros at both ends
    const int dir = bid >> 7;
    const int rem = bid & 127;
    const int b = rem >> 5, ch = rem & 31;
    const bool rev = (dir == 1);
    const float* g1p = x + ((size_t)b * 12 * NF + (3 * dir + 0) * NF + ch) * plane;
    const float* g2p = x + ((size_t)b * 12 * NF + (3 * dir + 1) * NF + ch) * plane;
    const float* g3p = x + ((size_t)b * 12 * NF + (3 * dir + 2) * NF + ch) * plane;
    const float* mp  = mask + ((size_t)b * NF + ch) * plane;
    float* wdir = ws + (size_t)dir * P + ((size_t)b * NF + ch) * plane;

    for (int i = tid; i < 2 * (HW + 2); i += 256) (&hb[0][0])[i] = 0.0f;

    float hreg = 0.0f;
    int cur = 0;
    float res[TCOLS], prev[TCOLS];
    int pt0 = 0;
    const int r0 = tid >> 1, cc = tid & 1;  // 2 threads per row for tile loads
    const float* ps[4] = {g1p, g2p, g3p, mp};
    for (int tile = 0; tile < HW / TCOLS; ++tile) {
      const int t0 = rev ? (HW - TCOLS - tile * TCOLS) : (tile * TCOLS);
      __syncthreads();  // prior readers done (also publishes hb init)
      if (tile > 0) {   // store previous tile's results; drained with the
                        // tile loads at the next barrier (off critical path)
        float4 v0 = {prev[0], prev[1], prev[2], prev[3]};
        float4 v1 = {prev[4], prev[5], prev[6], prev[7]};
        *(float4*)(wdir + (size_t)tid * HW + pt0) = v0;
        *(float4*)(wdir + (size_t)tid * HW + pt0 + 4) = v1;
      }
#pragma unroll
      for (int p = 0; p < 4; ++p) {
#pragma unroll
        for (int half = 0; half < 2; ++half) {
          const int r = r0 + half * 128;
          const float4 v = *(const float4*)(ps[p] + (size_t)r * HW + t0 + cc * 4);
          tl[p][cc * 4 + 0][r] = v.x;
          tl[p][cc * 4 + 1][r] = v.y;
          tl[p][cc * 4 + 2][r] = v.z;
          tl[p][cc * 4 + 3][r] = v.w;
        }
      }
      __syncthreads();
#pragma unroll
      for (int j = 0; j < TCOLS; ++j) {
        const int col = rev ? (TCOLS - 1 - j) : j;
        const float a  = tl[0][col][tid];
        const float g2 = tl[1][col][tid];
        const float c  = tl[2][col][tid];
        const float xm = tl[3][col][tid];
        const float hm = hb[cur][tid];
        const float hp = hb[cur][tid + 2];
        const float h = stepf(a, g2, c, xm, hm, hreg, hp);
        hb[cur ^ 1][tid + 1] = h;
        hreg = h;
        res[col] = h;
        __syncthreads();  // publish hb[cur^1]; protect WAR on hb[cur]
        cur ^= 1;
      }
#pragma unroll
      for (int k = 0; k < TCOLS; ++k) prev[k] = res[k];
      pt0 = t0;
    }
    {  // final tile store
      float4 v0 = {prev[0], prev[1], prev[2], prev[3]};
      float4 v1 = {prev[4], prev[5], prev[6], prev[7]};
      *(float4*)(wdir + (size_t)tid * HW + pt0) = v0;
      *(float4*)(wdir + (size_t)tid * HW + pt0 + 4) = v1;
    }
  } else {
    // ---------- vertical dirs 2 (fwd) / 3 (rev): one wave per slice ---------
    const int lane = tid & 63;
    const int sid = (bid - 256) * 4 + (tid >> 6);  // 0..255
    const int dir = 2 + (sid >> 7);
    const int rem = sid & 127;
    const int b = rem >> 5, ch = rem & 31;
    const bool rev = (dir == 3);
    const float* g1p = x + ((size_t)b * 12 * NF + (3 * dir + 0) * NF + ch) * plane;
    const float* g2p = x + ((size_t)b * 12 * NF + (3 * dir + 1) * NF + ch) * plane;
    const float* g3p = x + ((size_t)b * 12 * NF + (3 * dir + 2) * NF + ch) * plane;
    const float* mp  = mask + ((size_t)b * NF + ch) * plane;
    float* wdir = ws + (size_t)dir * P + ((size_t)b * NF + ch) * plane;

    const int koff = lane * 4;  // lane owns w = 4*lane .. 4*lane+3
    float4 hv = {0.f, 0.f, 0.f, 0.f};
    float4 Ab[4], Bb[4], Cb[4], Xb[4];  // depth-4 prefetch ring
#pragma unroll
    for (int p = 0; p < 4; ++p) {
      const int t = rev ? (HW - 1 - p) : p;
      const size_t ro = (size_t)t * HW + koff;
      Ab[p] = *(const float4*)(g1p + ro);
      Bb[p] = *(const float4*)(g2p + ro);
      Cb[p] = *(const float4*)(g3p + ro);
      Xb[p] = *(const float4*)(mp + ro);
    }

#define VSTEP(s, ph)                                                        \
  {                                                                         \
    const int t = rev ? (HW - 1 - (s)) : (s);                               \
    const float4 A = Ab[ph], Bv = Bb[ph], Cv = Cb[ph], X = Xb[ph];          \
    float left = __shfl_up(hv.w, 1);                                        \
    if (lane == 0) left = 0.f;                                              \
    float right = __shfl_down(hv.x, 1);                                     \
    if (lane == 63) right = 0.f;                                            \
    float4 hn;                                                              \
    hn.x = stepf(A.x, Bv.x, Cv.x, X.x, left, hv.x, hv.y);                   \
    hn.y = stepf(A.y, Bv.y, Cv.y, X.y, hv.x, hv.y, hv.z);                   \
    hn.z = stepf(A.z, Bv.z, Cv.z, X.z, hv.y, hv.z, hv.w);                   \
    hn.w = stepf(A.w, Bv.w, Cv.w, X.w, hv.z, hv.w, right);                  \
    *(float4*)(wdir + (size_t)t * HW + koff) = hn;                          \
    const int sn = (s) + 4;                                                 \
    if (sn < HW) {                                                          \
      const int tn = rev ? (HW - 1 - sn) : sn;                              \
      const size_t ro = (size_t)tn * HW + koff;                             \
      Ab[ph] = *(const float4*)(g1p + ro);                                  \
      Bb[ph] = *(const float4*)(g2p + ro);                                  \
      Cb[ph] = *(const float4*)(g3p + ro);                                  \
      Xb[ph] = *(const float4*)(mp + ro);                                   \
    }                                                                       \
    hv = hn;                                                                \
  }

    for (int s = 0; s < HW; s += 4) {
      VSTEP(s + 0, 0);
      VSTEP(s + 1, 1);
      VSTEP(s + 2, 2);
      VSTEP(s + 3, 3);
    }
#undef VSTEP
  }
}

__global__ __launch_bounds__(256) void spn_combine(
    const float4* __restrict__ w0, const float4* __restrict__ w1,
    const float4* __restrict__ w2, const float4* __restrict__ w3,
    float4* __restrict__ o) {
  const int i = blockIdx.x * 256 + threadIdx.x;
  const float4 a = w0[i], b = w1[i], c = w2[i], d = w3[i];
  float4 r;
  r.x = fmaxf(fmaxf(a.x, b.x), fmaxf(c.x, d.x));
  r.y = fmaxf(fmaxf(a.y, b.y), fmaxf(c.y, d.y));
  r.z = fmaxf(fmaxf(a.z, b.z), fmaxf(c.z, d.z));
  r.w = fmaxf(fmaxf(a.w, b.w), fmaxf(c.w, d.w));
  o[i] = r;
}

// ================= fallback path (previous passing version) =================
__global__ __launch_bounds__(256) void spn_scan_atomic(
    const float* __restrict__ x, const float* __restrict__ mask,
    unsigned* __restrict__ out) {
  const int bid = blockIdx.x;
  const int tid = threadIdx.x;
  __shared__ float tl[4][TCOLS][HW];
  __shared__ float hb[2][HW + 2];
  const size_t plane = (size_t)HW * HW;

  if (bid < 256) {
    const int dir = bid >> 7;
    const int rem = bid & 127;
    const int b = rem >> 5, ch = rem & 31;
    const bool rev = (dir == 1);
    const float* g1p = x + ((size_t)b * 12 * NF + (3 * dir + 0) * NF + ch) * plane;
    const float* g2p = x + ((size_t)b * 12 * NF + (3 * dir + 1) * NF + ch) * plane;
    const float* g3p = x + ((size_t)b * 12 * NF + (3 * dir + 2) * NF + ch) * plane;
    const float* mp  = mask + ((size_t)b * NF + ch) * plane;
    unsigned* op = out + ((size_t)b * NF + ch) * plane;

    for (int i = tid; i < 2 * (HW + 2); i += 256) (&hb[0][0])[i] = 0.0f;

    float hreg = 0.0f;
    int cur = 0;
    const int r0 = tid >> 1, cc = tid & 1;
    const float* ps[4] = {g1p, g2p, g3p, mp};
    for (int tile = 0; tile < HW / TCOLS; ++tile) {
      const int t0 = rev ? (HW - TCOLS - tile * TCOLS) : (tile * TCOLS);
      __syncthreads();
#pragma unroll
      for (int p = 0; p < 4; ++p) {
#pragma unroll
        for (int half = 0; half < 2; ++half) {
          const int r = r0 + half * 128;
          const float4 v = *(const float4*)(ps[p] + (size_t)r * HW + t0 + cc * 4);
          tl[p][cc * 4 + 0][r] = v.x;
          tl[p][cc * 4 + 1][r] = v.y;
          tl[p][cc * 4 + 2][r] = v.z;
          tl[p][cc * 4 + 3][r] = v.w;
        }
      }
      __syncthreads();
      for (int j = 0; j < TCOLS; ++j) {
        const int col = rev ? (TCOLS - 1 - j) : j;
        const int t = t0 + col;
        const float a  = tl[0][col][tid];
        const float g2 = tl[1][col][tid];
        const float c  = tl[2][col][tid];
        const float xm = tl[3][col][tid];
        const float hm = hb[cur][tid];
        const float hp = hb[cur][tid + 2];
        const float h = stepf(a, g2, c, xm, hm, hreg, hp);
        hb[cur ^ 1][tid + 1] = h;
        hreg = h;
        atomicMax(op + (size_t)tid * HW + t, enc(h));
        __syncthreads();
        cur ^= 1;
      }
    }
  } else {
    if (tid >= 64) return;
    const int lane = tid;
    const int vb = bid - 256;
    const int dir = 2 + (vb >> 7);
    const int rem = vb & 127;
    const int b = rem >> 5, ch = rem & 31;
    const bool rev = (dir == 3);
    const float* g1p = x + ((size_t)b * 12 * NF + (3 * dir + 0) * NF + ch) * plane;
    const float* g2p = x + ((size_t)b * 12 * NF + (3 * dir + 1) * NF + ch) * plane;
    const float* g3p = x + ((size_t)b * 12 * NF + (3 * dir + 2) * NF + ch) * plane;
    const float* mp  = mask + ((size_t)b * NF + ch) * plane;
    unsigned* op = out + ((size_t)b * NF + ch) * plane;

    float4 hv = {0.f, 0.f, 0.f, 0.f};
    int t = rev ? (HW - 1) : 0;
    const int koff = lane * 4;
    float4 a4 = *(const float4*)(g1p + (size_t)t * HW + koff);
    float4 b4 = *(const float4*)(g2p + (size_t)t * HW + koff);
    float4 c4 = *(const float4*)(g3p + (size_t)t * HW + koff);
    float4 x4 = *(const float4*)(mp  + (size_t)t * HW + koff);
    for (int step = 0; step < HW; ++step) {
      const float4 A = a4, B = b4, C = c4, X = x4;
      const int tn = rev ? (HW - 2 - step) : (step + 1);
      if (step + 1 < HW) {
        a4 = *(const float4*)(g1p + (size_t)tn * HW + koff);
        b4 = *(const float4*)(g2p + (size_t)tn * HW + koff);
        c4 = *(const float4*)(g3p + (size_t)tn * HW + koff);
        x4 = *(const float4*)(mp  + (size_t)tn * HW + koff);
      }
      float left = __shfl_up(hv.w, 1);
      if (lane == 0) left = 0.f;
      float right = __shfl_down(hv.x, 1);
      if (lane == 63) right = 0.f;
      float4 hn;
      hn.x = stepf(A.x, B.x, C.x, X.x, left, hv.x, hv.y);
      hn.y = stepf(A.y, B.y, C.y, X.y, hv.x, hv.y, hv.z);
      hn.z = stepf(A.z, B.z, C.z, X.z, hv.y, hv.z, hv.w);
      hn.w = stepf(A.w, B.w, C.w, X.w, hv.z, hv.w, right);
      unsigned* o = op + (size_t)t * HW + koff;
      atomicMax(o + 0, enc(hn.x));
      atomicMax(o + 1, enc(hn.y));
      atomicMax(o + 2, enc(hn.z));
      atomicMax(o + 3, enc(hn.w));
      hv = hn;
      t = tn;
    }
  }
}

__global__ __launch_bounds__(256) void spn_decode(unsigned* __restrict__ o) {
  const int i = blockIdx.x * 256 + threadIdx.x;
  uint4 v = ((uint4*)o)[i];
  float4 f;
  f.x = dec(v.x); f.y = dec(v.y); f.z = dec(v.z); f.w = dec(v.w);
  ((float4*)o)[i] = f;
}

extern "C" void kernel_launch(void* const* d_in, const int* in_sizes, int n_in,
                              void* d_out, int out_size, void* d_ws, size_t ws_size,
                              hipStream_t stream) {
  const float* x = (const float*)d_in[0];     // [4,384,256,256] f32
  const float* mask = (const float*)d_in[1];  // [4,32,256,256] f32
  (void)in_sizes; (void)n_in;
  const size_t need = (size_t)4 * out_size * sizeof(float);
  if (ws_size >= need) {
    float* ws = (float*)d_ws;
    spn_scan_ws<<<320, 256, 0, stream>>>(x, mask, ws);
    const size_t P4 = (size_t)out_size / 4;  // float4 count per buffer
    spn_combine<<<out_size / 1024, 256, 0, stream>>>(
        (const float4*)ws, (const float4*)(ws + (size_t)out_size),
        (const float4*)(ws + 2 * (size_t)out_size),
        (const float4*)(ws + 3 * (size_t)out_size), (float4*)d_out);
    (void)P4;
  } else {
    hipMemsetAsync(d_out, 0, (size_t)out_size * sizeof(float), stream);
    spn_scan_atomic<<<512, 256, 0, stream>>>(x, mask, (unsigned*)d_out);
    spn_decode<<<out_size / 1024, 256, 0, stream>>>((unsigned*)d_out);
  }
}